// Round 10
// baseline (365.425 us; speedup 1.0000x reference)
//
#include <hip/hip_runtime.h>
#include <hip/hip_bf16.h>
#include <hip/hip_fp16.h>

#define T_DIM 2048
#define B_DIM 32
#define LIS_DIM 1024
#define SPE_DIM 1024
#define ATT_DIM 512

typedef _Float16 f16x8 __attribute__((ext_vector_type(8)));
typedef _Float16 f16x4 __attribute__((ext_vector_type(4)));
typedef float f32x4 __attribute__((ext_vector_type(4)));

// K0: prep. Blocks 0..63: pack W into MFMA-fragment order
//   WTf_f16x8[((mat*32+ct)*32+ks)*64 + lane] : h[j] = W[ks*32+hi*8+j][ct*16+lo]
// Blocks 64..95: q[b][a] = relu(spe[b]·W_proj[:,a] + b_proj[a])
__global__ void prep_kernel(const float* __restrict__ Ws,
                            const float* __restrict__ Wv,
                            _Float16* __restrict__ WTf,
                            const float* __restrict__ spe,
                            const float* __restrict__ Wp,
                            const float* __restrict__ bp,
                            float* __restrict__ q) {
  int blk = blockIdx.x;
  int tid = threadIdx.x;
  if (blk < 64) {
    __shared__ float t17[1024 * 17];
    int mat = blk >> 5, ct = blk & 31;
    const float* W = mat ? Wv : Ws;
    for (int e = tid; e < 16384; e += 256) {
      int k = e >> 4, c = e & 15;
      t17[k * 17 + c] = W[(size_t)k * ATT_DIM + ct * 16 + c];
    }
    __syncthreads();
    int wv4 = tid >> 6, lane = tid & 63, lo = lane & 15, hi = lane >> 4;
    for (int ks = wv4; ks < 32; ks += 4) {
      f16x8 h;
#pragma unroll
      for (int j = 0; j < 8; ++j)
        h[j] = (_Float16)t17[(ks * 32 + hi * 8 + j) * 17 + lo];
      ((f16x8*)WTf)[((size_t)((mat * 32 + ct) * 32 + ks)) * 64 + lane] = h;
    }
  } else {
    __shared__ float s[SPE_DIM];
    int b = blk - 64;
    for (int i = tid; i < SPE_DIM; i += 256) s[i] = spe[(size_t)b * SPE_DIM + i];
    __syncthreads();
    for (int a = tid; a < ATT_DIM; a += 256) {
      float acc = bp[a];
      for (int l = 0; l < SPE_DIM; ++l)
        acc = fmaf(s[l], Wp[(size_t)l * ATT_DIM + a], acc);
      q[(size_t)b * ATT_DIM + a] = fmaxf(acc, 0.f);
    }
  }
}

// K2: dual GEMM, M=64 (one b, 64 t's), 4-phase-per-chunk schedule:
// per phase: {next-phase W loads || 1 NT stage load || 4 ds_read -> barrier ->
//             lgkmcnt(0)+sched_barrier -> setprio(1) 32 MFMA setprio(0) -> barrier}
__global__ __launch_bounds__(512, 2)
void dual_gemm_kernel(const float* __restrict__ x,
                      const _Float16* __restrict__ WTf,
                      const float* __restrict__ bs,
                      const float* __restrict__ bv,
                      const float* __restrict__ q,
                      float* __restrict__ scores,
                      _Float16* __restrict__ vals_p) {
  __shared__ __align__(16) char A_lds[2][16384];  // 64 rows x 128k f16, XOR swz
  __shared__ float bk_s[ATT_DIM], bv_s[ATT_DIM], q_s[ATT_DIM];
  __shared__ float red_s[64];

  const int tid = threadIdx.x;
  const int blk = blockIdx.x;
  const int b = blk & 31;
  const int tc = blk >> 5;
  const int t0 = tc * 64;

  bk_s[tid] = bs[tid];
  bv_s[tid] = bv[tid];
  q_s[tid] = q[(size_t)b * ATT_DIM + tid];
  if (tid < 64) red_s[tid] = 0.f;

  const float* xb = x + (size_t)b * LIS_DIM;
  const int wv = tid >> 6;
  const int lane = tid & 63;
  const int lo = lane & 15;
  const int hi = lane >> 4;

  f32x4 sl[4];  // in-flight stage registers (one filled per phase)
  auto stage_load_one = [&](int c, int it) {
    const int k0 = c * 128;
    int idx = it * 512 + tid;
    int row = idx >> 5;
    int c4 = idx & 31;
    sl[it] = __builtin_nontemporal_load(
        (const f32x4*)(xb + (size_t)(t0 + row) * (B_DIM * LIS_DIM) + k0) + c4);
  };
  auto stage_write = [&](int c) {
    char* buf = A_lds[c & 1];
#pragma unroll
    for (int it = 0; it < 4; ++it) {
      int idx = it * 512 + tid;
      int row = idx >> 5;
      int c4 = idx & 31;
      f16x4 h;
      h[0] = (_Float16)sl[it][0]; h[1] = (_Float16)sl[it][1];
      h[2] = (_Float16)sl[it][2]; h[3] = (_Float16)sl[it][3];
      int off = (row * 256 + c4 * 8) ^ ((row & 7) << 4);
      *(f16x4*)(buf + off) = h;
    }
  };

  f32x4 kacc[4][4], vacc[4][4];
#pragma unroll
  for (int m = 0; m < 4; ++m)
#pragma unroll
    for (int n = 0; n < 4; ++n) {
      kacc[m][n] = (f32x4){0.f, 0.f, 0.f, 0.f};
      vacc[m][n] = (f32x4){0.f, 0.f, 0.f, 0.f};
    }

  // prologue: full stage of chunk 0
#pragma unroll
  for (int it = 0; it < 4; ++it) stage_load_one(0, it);
  stage_write(0);
  asm volatile("s_waitcnt lgkmcnt(0)" ::: "memory");
  __builtin_amdgcn_s_barrier();

  const f16x8* Wf = (const f16x8*)WTf;
  f16x8 wkf[2][4], wvf[2][4];  // 1-phase-deep register pipe for W frags
#pragma unroll
  for (int n = 0; n < 4; ++n) {
    wkf[0][n] = Wf[(size_t)((wv * 4 + n) * 32 + 0) * 64 + lane];
    wvf[0][n] = Wf[(size_t)((32 + wv * 4 + n) * 32 + 0) * 64 + lane];
  }

  for (int c = 0; c < 8; ++c) {
    const char* buf = A_lds[c & 1];
#pragma unroll
    for (int kki = 0; kki < 4; ++kki) {
      const int ks = c * 4 + kki;
      const int kp = (ks + 1 < 32) ? ks + 1 : 31;
      const int cur = kki & 1, nxt = cur ^ 1;
      // issue next phase's W loads (normal loads; compiler vmcnt at first use)
#pragma unroll
      for (int n = 0; n < 4; ++n) {
        wkf[nxt][n] = Wf[(size_t)((wv * 4 + n) * 32 + kp) * 64 + lane];
        wvf[nxt][n] = Wf[(size_t)((32 + wv * 4 + n) * 32 + kp) * 64 + lane];
      }
      // issue one NT stage load for chunk c+1 (stays in flight across barriers)
      if (c < 7) stage_load_one(c + 1, kki);
      // ds_read current phase's x fragments
      f16x8 bx[4];
#pragma unroll
      for (int m = 0; m < 4; ++m) {
        int row = m * 16 + lo;
        int off = (row * 256 + kki * 64 + hi * 16) ^ ((row & 7) << 4);
        bx[m] = *(const f16x8*)(buf + off);
      }
      __builtin_amdgcn_s_barrier();
      asm volatile("s_waitcnt lgkmcnt(0)" ::: "memory");
      __builtin_amdgcn_sched_barrier(0);  // keep MFMAs below the wait (rule #18)
      __builtin_amdgcn_s_setprio(1);
#pragma unroll
      for (int n = 0; n < 4; ++n)
#pragma unroll
        for (int m = 0; m < 4; ++m) {
          kacc[m][n] = __builtin_amdgcn_mfma_f32_16x16x32_f16(wkf[cur][n], bx[m], kacc[m][n], 0, 0, 0);
          vacc[m][n] = __builtin_amdgcn_mfma_f32_16x16x32_f16(wvf[cur][n], bx[m], vacc[m][n], 0, 0, 0);
        }
      __builtin_amdgcn_s_setprio(0);
      __builtin_amdgcn_s_barrier();
    }
    if (c < 7) {
      stage_write(c + 1);  // vmcnt for sl handled by data-dep; writes other buffer
      asm volatile("s_waitcnt lgkmcnt(0)" ::: "memory");
      __builtin_amdgcn_s_barrier();
    }
  }

  // vals epilogue: packed lane-natural layout, non-temporal 8B stores
  _Float16* vp = vals_p + ((size_t)(b * 32 + tc) * 8 + wv) * 4096;
#pragma unroll
  for (int m = 0; m < 4; ++m)
#pragma unroll
    for (int n = 0; n < 4; ++n) {
      int col = wv * 64 + n * 16 + hi * 4;
      f16x4 h;
#pragma unroll
      for (int r = 0; r < 4; ++r)
        h[r] = (_Float16)fmaxf(vacc[m][n][r] + bv_s[col + r], 0.f);
      __builtin_nontemporal_store(h, (f16x4*)(vp + (m * 4 + n) * 256 + lane * 4));
    }

  // scores epilogue
  float sr[4] = {0.f, 0.f, 0.f, 0.f};
#pragma unroll
  for (int m = 0; m < 4; ++m)
#pragma unroll
    for (int n = 0; n < 4; ++n) {
      int col = wv * 64 + n * 16 + hi * 4;
#pragma unroll
      for (int r = 0; r < 4; ++r)
        sr[m] += q_s[col + r] * fmaxf(kacc[m][n][r] + bk_s[col + r], 0.f);
    }
#pragma unroll
  for (int m = 0; m < 4; ++m) {
    sr[m] += __shfl_xor(sr[m], 16, 64);
    sr[m] += __shfl_xor(sr[m], 32, 64);
    if (lane < 16) atomicAdd(&red_s[m * 16 + lo], sr[m]);
  }
  __syncthreads();
  if (tid < 64) scores[(size_t)b * T_DIM + t0 + tid] = red_s[tid];
}

// K3: masked softmax per b; writes attn f32 to out, zeroes context region of out
__global__ void softmax_kernel(const float* __restrict__ scores,
                               const int* __restrict__ llen,
                               float* __restrict__ attn_out,   // d_out + 16384
                               float* __restrict__ ctx_out) {  // d_out (zeroed here)
  __shared__ float rmax[4], rsum[4];
  int b = blockIdx.x, tid = threadIdx.x;
  int L = llen[b];
  float v[8];
  float mx = -1e30f;
  for (int i = 0; i < 8; ++i) {
    int t = i * 256 + tid;
    float s = scores[(size_t)b * T_DIM + t];
    if (t >= L) s -= 100.f;
    v[i] = s;
    mx = fmaxf(mx, s);
  }
  for (int d = 1; d < 64; d <<= 1) mx = fmaxf(mx, __shfl_xor(mx, d, 64));
  if ((tid & 63) == 0) rmax[tid >> 6] = mx;
  __syncthreads();
  mx = fmaxf(fmaxf(rmax[0], rmax[1]), fmaxf(rmax[2], rmax[3]));
  float sum = 0.f;
  for (int i = 0; i < 8; ++i) { v[i] = expf(v[i] - mx); sum += v[i]; }
  for (int d = 1; d < 64; d <<= 1) sum += __shfl_xor(sum, d, 64);
  if ((tid & 63) == 0) rsum[tid >> 6] = sum;
  __syncthreads();
  sum = rsum[0] + rsum[1] + rsum[2] + rsum[3];
  float inv = 1.f / sum;
  for (int i = 0; i < 8; ++i) {
    int t = i * 256 + tid;
    attn_out[(size_t)b * T_DIM + t] = v[i] * inv;
  }
  for (int i = tid; i < ATT_DIM; i += 256) ctx_out[(size_t)b * ATT_DIM + i] = 0.f;
}

// K4: ctx[b][col] = sum_t attn[b][t] * vals[t][col], decoding packed layout.
__global__ __launch_bounds__(512)
void ctx_kernel(const _Float16* __restrict__ vals_p,
                const float* __restrict__ attn,
                float* __restrict__ ctx) {
  __shared__ float attn_s[256];
  int blk = blockIdx.x;
  int b = blk >> 3, tcg = blk & 7;
  int tid = threadIdx.x;
  int wv = tid >> 6, lane = tid & 63, lo = lane & 15, hi = lane >> 4;
  if (tid < 256) attn_s[tid] = attn[(size_t)b * T_DIM + tcg * 256 + tid];
  __syncthreads();
  float cacc[4][4] = {};
  for (int i = 0; i < 4; ++i) {
    int tc = tcg * 4 + i;
    const _Float16* vp = vals_p + ((size_t)(b * 32 + tc) * 8 + wv) * 4096;
#pragma unroll
    for (int m = 0; m < 4; ++m) {
      float w = attn_s[i * 64 + m * 16 + lo];
#pragma unroll
      for (int n = 0; n < 4; ++n) {
        f16x4 v = __builtin_nontemporal_load(
            (const f16x4*)(vp + (m * 4 + n) * 256 + lane * 4));
#pragma unroll
        for (int r = 0; r < 4; ++r) cacc[n][r] += w * (float)v[r];
      }
    }
  }
#pragma unroll
  for (int n = 0; n < 4; ++n)
#pragma unroll
    for (int r = 0; r < 4; ++r) {
      float v = cacc[n][r];
      v += __shfl_xor(v, 1, 64);
      v += __shfl_xor(v, 2, 64);
      v += __shfl_xor(v, 4, 64);
      v += __shfl_xor(v, 8, 64);
      if (lo == 0)
        atomicAdd(&ctx[(size_t)b * ATT_DIM + wv * 64 + n * 16 + hi * 4 + r], v);
    }
}

extern "C" void kernel_launch(void* const* d_in, const int* in_sizes, int n_in,
                              void* d_out, int out_size, void* d_ws, size_t ws_size,
                              hipStream_t stream) {
  const float* x   = (const float*)d_in[0];
  const float* spe = (const float*)d_in[1];
  const int*   len = (const int*)d_in[2];
  const float* Ws  = (const float*)d_in[4];
  const float* bs  = (const float*)d_in[5];
  const float* Wv  = (const float*)d_in[6];
  const float* bv  = (const float*)d_in[7];
  const float* Wp  = (const float*)d_in[8];
  const float* bp  = (const float*)d_in[9];
  float* out = (float*)d_out;  // [0,16384): context f32, [16384,81920): attn f32

  char* ws = (char*)d_ws;
  _Float16* WTf  = (_Float16*)ws;                            // 2 MB packed frags
  float* q       = (float*)(ws + (2u << 20));                // 64 KB
  float* scores  = (float*)(ws + (2u << 20) + (64u << 10));  // 256 KB
  _Float16* vals = (_Float16*)(ws + (4u << 20));             // 64 MB packed

  prep_kernel<<<dim3(96), dim3(256), 0, stream>>>(Ws, Wv, WTf, spe, Wp, bp, q);
  dual_gemm_kernel<<<dim3(1024), dim3(512), 0, stream>>>(
      x, WTf, bs, bv, q, scores, vals);
  softmax_kernel<<<dim3(32), dim3(256), 0, stream>>>(scores, len, out + 16384, out);
  ctx_kernel<<<dim3(256), dim3(512), 0, stream>>>(vals, out + 16384, out);
}

// Round 11
// 298.256 us; speedup vs baseline: 1.2252x; 1.2252x over previous
//
#include <hip/hip_runtime.h>
#include <hip/hip_bf16.h>
#include <hip/hip_fp16.h>

#define T_DIM 2048
#define B_DIM 32
#define LIS_DIM 1024
#define SPE_DIM 1024
#define ATT_DIM 512

typedef _Float16 f16x8 __attribute__((ext_vector_type(8)));
typedef _Float16 f16x4 __attribute__((ext_vector_type(4)));
typedef float f32x4 __attribute__((ext_vector_type(4)));
typedef float f32x16 __attribute__((ext_vector_type(16)));
typedef unsigned int u32;

// K0: prep.
//  blocks 0..63   : pack W (64x256 slice) into 32x32x16 A-fragment order:
//    frag[(((nb*16+c)*4+ks)*8+ct)*64+lane].h[j] =
//        W_mat[c*64+ks*16+(lane>>5)*8+j][(nb&1)*256+ct*32+(lane&31)]
//  blocks 64..95  : q[b][a] = relu(spe[b]·W_proj[:,a]+b_proj[a])
//  blocks 96..103 : zero scores (atomic accumulator, must be zero every launch)
__global__ __launch_bounds__(256)
void prep_kernel(const float* __restrict__ Ws, const float* __restrict__ Wv,
                 _Float16* __restrict__ WTf, const float* __restrict__ spe,
                 const float* __restrict__ Wp, const float* __restrict__ bp,
                 float* __restrict__ q, float* __restrict__ scores) {
  int p = blockIdx.x, tid = threadIdx.x;
  if (p < 64) {
    __shared__ float wlds[64 * 257];
    int nb = p >> 4, c = p & 15;
    const float* W = (nb >> 1) ? Wv : Ws;
    int col0 = (nb & 1) * 256;
    for (int i = 0; i < 64; ++i) {
      int e = i * 256 + tid;
      int r = e >> 8, cl = e & 255;
      wlds[r * 257 + cl] = W[(size_t)(c * 64 + r) * ATT_DIM + col0 + cl];
    }
    __syncthreads();
    int lane = tid & 63, ks = tid >> 6, hk = lane >> 5, cs = lane & 31;
#pragma unroll
    for (int ct = 0; ct < 8; ++ct) {
      f16x8 h;
#pragma unroll
      for (int jj = 0; jj < 8; ++jj)
        h[jj] = (_Float16)wlds[(ks * 16 + hk * 8 + jj) * 257 + ct * 32 + cs];
      ((f16x8*)WTf)[(size_t)(((p * 4 + ks) * 8 + ct)) * 64 + lane] = h;
    }
  } else if (p < 96) {
    __shared__ float s[SPE_DIM];
    int b = p - 64;
    for (int i = tid; i < SPE_DIM; i += 256) s[i] = spe[(size_t)b * SPE_DIM + i];
    __syncthreads();
    for (int a = tid; a < ATT_DIM; a += 256) {
      float acc = bp[a];
      for (int l = 0; l < SPE_DIM; ++l)
        acc = fmaf(s[l], Wp[(size_t)l * ATT_DIM + a], acc);
      q[(size_t)b * ATT_DIM + a] = fmaxf(acc, 0.f);
    }
  } else {
    int base = (p - 96) * 8192;
    for (int i = 0; i < 32; ++i) scores[base + i * 256 + tid] = 0.f;
  }
}

// K1: 256x256-tile GEMM, nb in {0,1}: scores cols, {2,3}: vals cols.
// 4 nb-twins share one x tile via same-XCD scheduling. 1 barrier per K-chunk.
__global__ __launch_bounds__(512, 2)
void gemm_kernel(const float* __restrict__ x, const _Float16* __restrict__ WTf,
                 const float* __restrict__ bs, const float* __restrict__ bv,
                 const float* __restrict__ q, float* __restrict__ scores,
                 _Float16* __restrict__ vals_p) {
  __shared__ __align__(16) _Float16 A_lds[2][16384];  // 256r x 64k f16, swizzled
  __shared__ __align__(16) _Float16 W_lds[2][16384];  // [ks(4)][ct(8)][lane][8]
  __shared__ float bias_s[256], q_s[256], red_s[256];

  const int tid = threadIdx.x;
  const int raw = blockIdx.x;
  const int xcd = raw & 7;
  const int j   = raw >> 3;
  const int nb  = j & 3;            // twins (same tile) are XCD-local neighbors
  const int tile = (j >> 2) * 8 + xcd;   // [0,256)
  const int b   = tile >> 3;
  const int tm  = tile & 7;
  const int t0  = tm * 256;
  const bool is_scores = (nb < 2);

  const float* bias_src = is_scores ? (bs + (nb & 1) * 256) : (bv + (nb & 1) * 256);
  if (tid < 256) {
    bias_s[tid] = bias_src[tid];
    red_s[tid] = 0.f;
    if (is_scores) q_s[tid] = q[(size_t)b * ATT_DIM + nb * 256 + tid];
  }

  const int wv = tid >> 6, lane = tid & 63;
  const int wr = wv >> 2, wc = wv & 3;
  const int ts = lane & 31, hk = lane >> 5;

  const float* xb = x + (size_t)b * LIS_DIM;
  f32x4 sl[8];
  auto stage_load = [&](int c) {
#pragma unroll
    for (int i = 0; i < 8; ++i) {
      int e = i * 512 + tid;
      int row = e >> 4, q4 = e & 15;
      sl[i] = *((const f32x4*)(xb + (size_t)(t0 + row) * (B_DIM * LIS_DIM) + c * 64) + q4);
    }
  };
  auto stage_write = [&](int bufi) {
    char* buf = (char*)A_lds[bufi];
#pragma unroll
    for (int i = 0; i < 8; ++i) {
      int e = i * 512 + tid;
      int row = e >> 4, q4 = e & 15;
      f16x4 h;
      h[0] = (_Float16)sl[i][0]; h[1] = (_Float16)sl[i][1];
      h[2] = (_Float16)sl[i][2]; h[3] = (_Float16)sl[i][3];
      *(f16x4*)(buf + row * 128 + ((q4 * 8) ^ ((row & 7) << 4))) = h;
    }
  };
  auto w_prefetch = [&](int c, int bufi) {
    const char* slice = (const char*)WTf + ((size_t)(nb * 16 + c)) * 32768;
    char* lb = (char*)W_lds[bufi] + wv * 1024;
#pragma unroll
    for (int i = 0; i < 4; ++i) {
      __builtin_amdgcn_global_load_lds(
          (const __attribute__((address_space(1))) u32*)(slice + i * 8192 + tid * 16),
          (__attribute__((address_space(3))) u32*)(lb + i * 8192), 16, 0, 0);
    }
  };

  f32x16 acc[4][2];
#pragma unroll
  for (int m = 0; m < 4; ++m)
#pragma unroll
    for (int n = 0; n < 2; ++n)
      acc[m][n] = (f32x16)(0.f);

  // prologue: chunk 0 fully staged
  w_prefetch(0, 0);
  stage_load(0);
  stage_write(0);
  asm volatile("s_waitcnt vmcnt(0) lgkmcnt(0)" ::: "memory");
  __builtin_amdgcn_s_barrier();

  for (int c = 0; c < 16; ++c) {
    const int bi = c & 1;
    if (c < 15) { w_prefetch(c + 1, bi ^ 1); stage_load(c + 1); }
    const char* Ab = (const char*)A_lds[bi];
    const char* Wb = (const char*)W_lds[bi];
#pragma unroll
    for (int ks = 0; ks < 4; ++ks) {
      f16x8 wf[2], bx[4];
#pragma unroll
      for (int n = 0; n < 2; ++n)
        wf[n] = *(const f16x8*)(Wb + (ks * 8 + wc * 2 + n) * 1024 + lane * 16);
#pragma unroll
      for (int m = 0; m < 4; ++m) {
        int row = wr * 128 + m * 32 + ts;
        bx[m] = *(const f16x8*)(Ab + row * 128 + ((ks * 32 + hk * 16) ^ ((row & 7) << 4)));
      }
      __builtin_amdgcn_s_setprio(1);
#pragma unroll
      for (int n = 0; n < 2; ++n)
#pragma unroll
        for (int m = 0; m < 4; ++m)
          acc[m][n] = __builtin_amdgcn_mfma_f32_32x32x16_f16(wf[n], bx[m], acc[m][n], 0, 0, 0);
      __builtin_amdgcn_s_setprio(0);
    }
    if (c < 15) stage_write(bi ^ 1);
    asm volatile("s_waitcnt vmcnt(0) lgkmcnt(0)" ::: "memory");
    __builtin_amdgcn_s_barrier();
  }

  // C/D (32x32): out-col i = (reg&3)+8*(reg>>2)+4*hk, t = base + (lane&31)
  if (is_scores) {
#pragma unroll
    for (int m = 0; m < 4; ++m) {
      float s = 0.f;
#pragma unroll
      for (int n = 0; n < 2; ++n)
#pragma unroll
        for (int rg = 0; rg < 16; ++rg) {
          int cl = wc * 64 + n * 32 + (rg & 3) + 8 * (rg >> 2) + 4 * hk;
          s += q_s[cl] * fmaxf(acc[m][n][rg] + bias_s[cl], 0.f);
        }
      s += __shfl_xor(s, 32, 64);
      if (lane < 32) atomicAdd(&red_s[wr * 128 + m * 32 + ts], s);
    }
    __syncthreads();
    if (tid < 256) atomicAdd(&scores[(size_t)b * T_DIM + t0 + tid], red_s[tid]);
  } else {
    _Float16* vb = vals_p + (((size_t)tile * 2 + (nb - 2)) * 8 + wv) * 8192;
#pragma unroll
    for (int m = 0; m < 4; ++m)
#pragma unroll
      for (int n = 0; n < 2; ++n)
#pragma unroll
        for (int g = 0; g < 4; ++g) {
          f16x4 h;
#pragma unroll
          for (int r = 0; r < 4; ++r) {
            int cl = wc * 64 + n * 32 + 8 * g + 4 * hk + r;
            h[r] = (_Float16)fmaxf(acc[m][n][g * 4 + r] + bias_s[cl], 0.f);
          }
          *(f16x4*)(vb + (size_t)(((m * 2 + n) * 4 + g) * 64 + lane) * 4) = h;
        }
  }
}

// K2: masked softmax per b; writes attn f32 to out
__global__ void softmax_kernel(const float* __restrict__ scores,
                               const int* __restrict__ llen,
                               float* __restrict__ attn_out) {
  __shared__ float rmax[4], rsum[4];
  int b = blockIdx.x, tid = threadIdx.x;
  int L = llen[b];
  float v[8];
  float mx = -1e30f;
  for (int i = 0; i < 8; ++i) {
    int t = i * 256 + tid;
    float s = scores[(size_t)b * T_DIM + t];
    if (t >= L) s -= 100.f;
    v[i] = s;
    mx = fmaxf(mx, s);
  }
  for (int d = 1; d < 64; d <<= 1) mx = fmaxf(mx, __shfl_xor(mx, d, 64));
  if ((tid & 63) == 0) rmax[tid >> 6] = mx;
  __syncthreads();
  mx = fmaxf(fmaxf(rmax[0], rmax[1]), fmaxf(rmax[2], rmax[3]));
  float sum = 0.f;
  for (int i = 0; i < 8; ++i) { v[i] = expf(v[i] - mx); sum += v[i]; }
  for (int d = 1; d < 64; d <<= 1) sum += __shfl_xor(sum, d, 64);
  if ((tid & 63) == 0) rsum[tid >> 6] = sum;
  __syncthreads();
  sum = rsum[0] + rsum[1] + rsum[2] + rsum[3];
  float inv = 1.f / sum;
  for (int i = 0; i < 8; ++i)
    attn_out[(size_t)b * T_DIM + i * 256 + tid] = v[i] * inv;
}

// K3: ctx[b][col] = sum_t attn[b][t]*vals[t][col]; decodes packed layout,
// each output col written exactly once (no atomics).
__global__ __launch_bounds__(512)
void ctx_kernel(const _Float16* __restrict__ vals_p,
                const float* __restrict__ attn,
                float* __restrict__ ctx) {
  __shared__ float attn_s[T_DIM];
  int blk = blockIdx.x;
  int b = blk >> 1, nb2 = blk & 1;
  int tid = threadIdx.x;
#pragma unroll
  for (int i = 0; i < 4; ++i)
    attn_s[i * 512 + tid] = attn[(size_t)b * T_DIM + i * 512 + tid];
  __syncthreads();
  int w = tid >> 6, L = tid & 63;
  int wc = w >> 1, n = w & 1, h = L >> 5, ts = L & 31;
  float acc[4][4] = {};
  for (int tm = 0; tm < 8; ++tm) {
    int tile = b * 8 + tm;
#pragma unroll
    for (int wr = 0; wr < 2; ++wr) {
      const _Float16* base = vals_p + (((size_t)tile * 2 + nb2) * 8 + (wr * 4 + wc)) * 8192;
#pragma unroll
      for (int m = 0; m < 4; ++m) {
        float a = attn_s[tm * 256 + wr * 128 + m * 32 + ts];
#pragma unroll
        for (int g = 0; g < 4; ++g) {
          f16x4 v = *(const f16x4*)(base + (size_t)(((m * 2 + n) * 4 + g) * 64 + L) * 4);
#pragma unroll
          for (int r = 0; r < 4; ++r) acc[g][r] += a * (float)v[r];
        }
      }
    }
  }
#pragma unroll
  for (int g = 0; g < 4; ++g)
#pragma unroll
    for (int r = 0; r < 4; ++r) {
      float v2 = acc[g][r];
      v2 += __shfl_xor(v2, 1, 64);
      v2 += __shfl_xor(v2, 2, 64);
      v2 += __shfl_xor(v2, 4, 64);
      v2 += __shfl_xor(v2, 8, 64);
      v2 += __shfl_xor(v2, 16, 64);
      if (ts == 0)
        ctx[(size_t)b * ATT_DIM + nb2 * 256 + wc * 64 + n * 32 + 8 * g + 4 * h + r] = v2;
    }
}

extern "C" void kernel_launch(void* const* d_in, const int* in_sizes, int n_in,
                              void* d_out, int out_size, void* d_ws, size_t ws_size,
                              hipStream_t stream) {
  const float* x   = (const float*)d_in[0];
  const float* spe = (const float*)d_in[1];
  const int*   len = (const int*)d_in[2];
  const float* Ws  = (const float*)d_in[4];
  const float* bs  = (const float*)d_in[5];
  const float* Wv  = (const float*)d_in[6];
  const float* bv  = (const float*)d_in[7];
  const float* Wp  = (const float*)d_in[8];
  const float* bp  = (const float*)d_in[9];
  float* out = (float*)d_out;  // [0,16384): context f32, [16384,81920): attn f32

  char* ws = (char*)d_ws;
  _Float16* WTf  = (_Float16*)ws;                            // 2 MB packed frags
  float* q       = (float*)(ws + (2u << 20));                // 64 KB
  float* scores  = (float*)(ws + (2u << 20) + (64u << 10));  // 256 KB
  _Float16* vals = (_Float16*)(ws + (4u << 20));             // 64 MB packed

  prep_kernel<<<dim3(104), dim3(256), 0, stream>>>(Ws, Wv, WTf, spe, Wp, bp, q, scores);
  gemm_kernel<<<dim3(1024), dim3(512), 0, stream>>>(x, WTf, bs, bv, q, scores, vals);
  softmax_kernel<<<dim3(32), dim3(256), 0, stream>>>(scores, len, out + 16384);
  ctx_kernel<<<dim3(64), dim3(512), 0, stream>>>(vals, out + 16384, out);
}

// Round 12
// 286.415 us; speedup vs baseline: 1.2759x; 1.0413x over previous
//
#include <hip/hip_runtime.h>
#include <hip/hip_bf16.h>
#include <hip/hip_fp16.h>

#define T_DIM 2048
#define B_DIM 32
#define LIS_DIM 1024
#define SPE_DIM 1024
#define ATT_DIM 512

typedef _Float16 f16x8 __attribute__((ext_vector_type(8)));
typedef _Float16 f16x4 __attribute__((ext_vector_type(4)));
typedef float f32x4 __attribute__((ext_vector_type(4)));
typedef float f32x16 __attribute__((ext_vector_type(16)));
typedef unsigned int u32;

// K0: prep.
//  blocks 0..63   : pack W into 32x32x16 A-frag order, BK=32 chunked:
//    frag_f16x8[(((nb*32+c5)*2+ks2)*8+ct)*64+lane].h[j] =
//        W_mat[c5*32+ks2*16+(lane>>5)*8+j][(nb&1)*256+ct*32+(lane&31)]
//  blocks 64..95  : q[b][a] = relu(spe[b]·W_proj[:,a]+b_proj[a])
//  blocks 96..103 : zero scores (atomic accumulator)
__global__ __launch_bounds__(256)
void prep_kernel(const float* __restrict__ Ws, const float* __restrict__ Wv,
                 _Float16* __restrict__ WTf, const float* __restrict__ spe,
                 const float* __restrict__ Wp, const float* __restrict__ bp,
                 float* __restrict__ q, float* __restrict__ scores) {
  int p = blockIdx.x, tid = threadIdx.x;
  if (p < 64) {
    __shared__ float wlds[64 * 257];
    int nb = p >> 4, c = p & 15;
    const float* W = (nb >> 1) ? Wv : Ws;
    int col0 = (nb & 1) * 256;
    for (int i = 0; i < 64; ++i) {
      int e = i * 256 + tid;
      int r = e >> 8, cl = e & 255;
      wlds[r * 257 + cl] = W[(size_t)(c * 64 + r) * ATT_DIM + col0 + cl];
    }
    __syncthreads();
    int lane = tid & 63, ks = tid >> 6, hk = lane >> 5, cs = lane & 31;
    int c5 = 2 * c + (ks >> 1), ks2 = ks & 1;
#pragma unroll
    for (int ct = 0; ct < 8; ++ct) {
      f16x8 h;
#pragma unroll
      for (int jj = 0; jj < 8; ++jj)
        h[jj] = (_Float16)wlds[(ks * 16 + hk * 8 + jj) * 257 + ct * 32 + cs];
      ((f16x8*)WTf)[(size_t)(((nb * 32 + c5) * 2 + ks2) * 8 + ct) * 64 + lane] = h;
    }
  } else if (p < 96) {
    __shared__ float s[SPE_DIM];
    int b = p - 64;
    for (int i = tid; i < SPE_DIM; i += 256) s[i] = spe[(size_t)b * SPE_DIM + i];
    __syncthreads();
    for (int a = tid; a < ATT_DIM; a += 256) {
      float acc = bp[a];
      for (int l = 0; l < SPE_DIM; ++l)
        acc = fmaf(s[l], Wp[(size_t)l * ATT_DIM + a], acc);
      q[(size_t)b * ATT_DIM + a] = fmaxf(acc, 0.f);
    }
  } else {
    int base = (p - 96) * 8192;
    for (int i = 0; i < 32; ++i) scores[base + i * 256 + tid] = 0.f;
  }
}

// K1: 128x256-tile GEMM, 4 waves/block, 2 blocks/CU. nb in {0,1}: scores cols,
// {2,3}: vals cols; 4 nb-twins share one x tile via same-XCD swizzle.
// W: 3-deep global_load_lds pipe, never drained to vmcnt(0) in the loop.
__global__ __launch_bounds__(256, 2)
void gemm_kernel(const float* __restrict__ x, const _Float16* __restrict__ WTf,
                 const float* __restrict__ bs, const float* __restrict__ bv,
                 const float* __restrict__ q, float* __restrict__ scores,
                 _Float16* __restrict__ vals_p) {
  __shared__ __align__(16) char A_lds[2][10240];   // 128r x 32k f16, 80B rows
  __shared__ __align__(16) char W_lds[3][16384];   // [ks2][ct8][lane][16B]
  __shared__ float bias_s[256], q_s[256], red_s[128];

  const int tid = threadIdx.x;
  const int raw = blockIdx.x;
  const int xcd = raw & 7;
  const int j   = raw >> 3;
  const int nb  = j & 3;
  const int tile = (j >> 2) * 8 + xcd;   // [0,512)
  const int b   = tile >> 4;
  const int tm  = tile & 15;
  const int t0  = tm * 128;
  const bool is_scores = (nb < 2);

  bias_s[tid] = is_scores ? bs[(nb & 1) * 256 + tid] : bv[(nb - 2) * 256 + tid];
  if (is_scores) q_s[tid] = q[(size_t)b * ATT_DIM + nb * 256 + tid];
  if (tid < 128) red_s[tid] = 0.f;

  const int wv = tid >> 6, lane = tid & 63;
  const int ts = lane & 31, hk = lane >> 5;

  const float* xb = x + (size_t)b * LIS_DIM;
  f32x4 sl[4];
  auto stage_load = [&](int c) {
#pragma unroll
    for (int i = 0; i < 4; ++i) {
      int e = i * 256 + tid;
      int row = e >> 3, q4 = e & 7;
      sl[i] = *((const f32x4*)(xb + (size_t)(t0 + row) * (B_DIM * LIS_DIM) + c * 32) + q4);
    }
  };
  auto stage_write = [&](int bufi) {
    char* buf = A_lds[bufi];
#pragma unroll
    for (int i = 0; i < 4; ++i) {
      int e = i * 256 + tid;
      int row = e >> 3, q4 = e & 7;
      f16x4 h;
      h[0] = (_Float16)sl[i][0]; h[1] = (_Float16)sl[i][1];
      h[2] = (_Float16)sl[i][2]; h[3] = (_Float16)sl[i][3];
      *(f16x4*)(buf + row * 80 + q4 * 8) = h;
    }
  };
  auto w_prefetch = [&](int c, int bufi) {
    const char* slice = (const char*)WTf + (size_t)(nb * 32 + c) * 16384;
    char* lb = W_lds[bufi] + wv * 1024;
#pragma unroll
    for (int i = 0; i < 4; ++i)
      __builtin_amdgcn_global_load_lds(
          (const __attribute__((address_space(1))) u32*)(slice + i * 4096 + tid * 16),
          (__attribute__((address_space(3))) u32*)(lb + i * 4096), 16, 0, 0);
  };

  f32x16 acc[4][2];
#pragma unroll
  for (int m = 0; m < 4; ++m)
#pragma unroll
    for (int n = 0; n < 2; ++n)
      acc[m][n] = (f32x16)(0.f);

  // prologue: W0 (oldest) -> A0 -> write A0 (implies W0 done) -> W1 in flight
  w_prefetch(0, 0);
  stage_load(0);
  stage_write(0);
  w_prefetch(1, 1);
  asm volatile("s_waitcnt lgkmcnt(0)" ::: "memory");
  __builtin_amdgcn_s_barrier();

  int wb = 0;
  for (int c = 0; c < 32; ++c) {
    const int bi = c & 1;
    if (c < 31) stage_load(c + 1);        // A first (older)...
    if (c < 30) {                          // ...then W(c+2) (stays in flight)
      int wt = wb + 2; if (wt >= 3) wt -= 3;
      w_prefetch(c + 2, wt);
    }
    const char* Ab = A_lds[bi];
    const char* Wb = W_lds[wb];
#pragma unroll
    for (int ks = 0; ks < 2; ++ks) {
      f16x8 wf[2], bx[4];
#pragma unroll
      for (int n = 0; n < 2; ++n)
        wf[n] = *(const f16x8*)(Wb + (ks * 8 + wv * 2 + n) * 1024 + lane * 16);
#pragma unroll
      for (int m = 0; m < 4; ++m) {
        int row = m * 32 + ts;
        bx[m] = *(const f16x8*)(Ab + row * 80 + ks * 32 + hk * 16);
      }
      __builtin_amdgcn_s_setprio(1);
#pragma unroll
      for (int n = 0; n < 2; ++n)
#pragma unroll
        for (int m = 0; m < 4; ++m)
          acc[m][n] = __builtin_amdgcn_mfma_f32_32x32x16_f16(wf[n], bx[m], acc[m][n], 0, 0, 0);
      __builtin_amdgcn_s_setprio(0);
    }
    if (c < 31) stage_write(bi ^ 1);  // implicit vmcnt(4): A(c+1)+W(c+1) done, W(c+2) flying
    asm volatile("s_waitcnt lgkmcnt(0)" ::: "memory");
    __builtin_amdgcn_s_barrier();
    ++wb; if (wb == 3) wb = 0;
  }

  // C/D (32x32): out-col = (rg&3)+8*(rg>>2)+4*hk, t = m*32 + (lane&31)
  if (is_scores) {
#pragma unroll
    for (int m = 0; m < 4; ++m) {
      float s = 0.f;
#pragma unroll
      for (int n = 0; n < 2; ++n)
#pragma unroll
        for (int rg = 0; rg < 16; ++rg) {
          int cl = wv * 64 + n * 32 + (rg & 3) + 8 * (rg >> 2) + 4 * hk;
          s += q_s[cl] * fmaxf(acc[m][n][rg] + bias_s[cl], 0.f);
        }
      s += __shfl_xor(s, 32, 64);
      if (lane < 32) atomicAdd(&red_s[m * 32 + ts], s);
    }
    __syncthreads();
    if (tid < 128) atomicAdd(&scores[(size_t)b * T_DIM + t0 + tid], red_s[tid]);
  } else {
    _Float16* vb = vals_p + ((size_t)(tile * 2 + (nb - 2)) * 4 + wv) * 8192;
#pragma unroll
    for (int m = 0; m < 4; ++m)
#pragma unroll
      for (int n = 0; n < 2; ++n)
#pragma unroll
        for (int g = 0; g < 4; ++g) {
          f16x4 h;
#pragma unroll
          for (int r = 0; r < 4; ++r) {
            int cl = wv * 64 + n * 32 + 8 * g + 4 * hk + r;
            h[r] = (_Float16)fmaxf(acc[m][n][g * 4 + r] + bias_s[cl], 0.f);
          }
          __builtin_nontemporal_store(
              h, (f16x4*)(vb + (size_t)(((m * 2 + n) * 4 + g) * 64 + lane) * 4));
        }
  }
}

// K2: masked softmax per b; writes attn f32 to out
__global__ void softmax_kernel(const float* __restrict__ scores,
                               const int* __restrict__ llen,
                               float* __restrict__ attn_out) {
  __shared__ float rmax[4], rsum[4];
  int b = blockIdx.x, tid = threadIdx.x;
  int L = llen[b];
  float v[8];
  float mx = -1e30f;
  for (int i = 0; i < 8; ++i) {
    int t = i * 256 + tid;
    float s = scores[(size_t)b * T_DIM + t];
    if (t >= L) s -= 100.f;
    v[i] = s;
    mx = fmaxf(mx, s);
  }
  for (int d = 1; d < 64; d <<= 1) mx = fmaxf(mx, __shfl_xor(mx, d, 64));
  if ((tid & 63) == 0) rmax[tid >> 6] = mx;
  __syncthreads();
  mx = fmaxf(fmaxf(rmax[0], rmax[1]), fmaxf(rmax[2], rmax[3]));
  float sum = 0.f;
  for (int i = 0; i < 8; ++i) { v[i] = expf(v[i] - mx); sum += v[i]; }
  for (int d = 1; d < 64; d <<= 1) sum += __shfl_xor(sum, d, 64);
  if ((tid & 63) == 0) rsum[tid >> 6] = sum;
  __syncthreads();
  sum = rsum[0] + rsum[1] + rsum[2] + rsum[3];
  float inv = 1.f / sum;
  for (int i = 0; i < 8; ++i)
    attn_out[(size_t)b * T_DIM + i * 256 + tid] = v[i] * inv;
}

// K3: ctx[b][col] = sum_t attn[b][t]*vals[t][col]; decodes packed layout,
// each output col written exactly once.
__global__ __launch_bounds__(512)
void ctx_kernel(const _Float16* __restrict__ vals_p,
                const float* __restrict__ attn,
                float* __restrict__ ctx) {
  __shared__ float attn_s[T_DIM];
  __shared__ float red[256];
  int blk = blockIdx.x;
  int b = blk >> 1, nb2 = blk & 1;
  int tid = threadIdx.x;
#pragma unroll
  for (int i = 0; i < 4; ++i)
    attn_s[i * 512 + tid] = attn[(size_t)b * T_DIM + i * 512 + tid];
  if (tid < 256) red[tid] = 0.f;
  __syncthreads();
  int wave = tid >> 6, lane = tid & 63;
  int w = wave >> 1, half = wave & 1, ts = lane & 31, hk = lane >> 5;
  float a2[2][4][4] = {};
  for (int t8 = 0; t8 < 8; ++t8) {
    int tm = half * 8 + t8;
    int tile = b * 16 + tm;
    const _Float16* base = vals_p + ((size_t)(tile * 2 + nb2) * 4 + w) * 8192;
#pragma unroll
    for (int m = 0; m < 4; ++m) {
      float a = attn_s[tm * 128 + m * 32 + ts];
#pragma unroll
      for (int n = 0; n < 2; ++n)
#pragma unroll
        for (int g = 0; g < 4; ++g) {
          f16x4 v = __builtin_nontemporal_load(
              (const f16x4*)(base + (size_t)(((m * 2 + n) * 4 + g) * 64 + lane) * 4));
#pragma unroll
          for (int r = 0; r < 4; ++r) a2[n][g][r] += a * (float)v[r];
        }
    }
  }
#pragma unroll
  for (int n = 0; n < 2; ++n)
#pragma unroll
    for (int g = 0; g < 4; ++g)
#pragma unroll
      for (int r = 0; r < 4; ++r) {
        float v2 = a2[n][g][r];
        v2 += __shfl_xor(v2, 1, 64);
        v2 += __shfl_xor(v2, 2, 64);
        v2 += __shfl_xor(v2, 4, 64);
        v2 += __shfl_xor(v2, 8, 64);
        v2 += __shfl_xor(v2, 16, 64);
        if (ts == 0) atomicAdd(&red[w * 64 + n * 32 + 8 * g + 4 * hk + r], v2);
      }
  __syncthreads();
  if (tid < 256) ctx[(size_t)b * ATT_DIM + nb2 * 256 + tid] = red[tid];
}

extern "C" void kernel_launch(void* const* d_in, const int* in_sizes, int n_in,
                              void* d_out, int out_size, void* d_ws, size_t ws_size,
                              hipStream_t stream) {
  const float* x   = (const float*)d_in[0];
  const float* spe = (const float*)d_in[1];
  const int*   len = (const int*)d_in[2];
  const float* Ws  = (const float*)d_in[4];
  const float* bs  = (const float*)d_in[5];
  const float* Wv  = (const float*)d_in[6];
  const float* bv  = (const float*)d_in[7];
  const float* Wp  = (const float*)d_in[8];
  const float* bp  = (const float*)d_in[9];
  float* out = (float*)d_out;  // [0,16384): context f32, [16384,81920): attn f32

  char* ws = (char*)d_ws;
  _Float16* WTf  = (_Float16*)ws;                            // 2 MB packed frags
  float* q       = (float*)(ws + (2u << 20));                // 64 KB
  float* scores  = (float*)(ws + (2u << 20) + (64u << 10));  // 256 KB
  _Float16* vals = (_Float16*)(ws + (4u << 20));             // 64 MB packed

  prep_kernel<<<dim3(104), dim3(256), 0, stream>>>(Ws, Wv, WTf, spe, Wp, bp, q, scores);
  gemm_kernel<<<dim3(2048), dim3(256), 0, stream>>>(x, WTf, bs, bv, q, scores, vals);
  softmax_kernel<<<dim3(32), dim3(256), 0, stream>>>(scores, len, out + 16384);
  ctx_kernel<<<dim3(64), dim3(512), 0, stream>>>(vals, out + 16384, out);
}